// Round 2
// baseline (1996.530 us; speedup 1.0000x reference)
//
#include <hip/hip_runtime.h>
#include <hip/hip_bf16.h>

// MeshConvNet on MI355X (gfx950) — precision-hardened round.
// h stored fp32 (bf16 fallback if ws too small); GEMM = split-bf16 3-product
// (A_hi*B_hi + A_lo*B_hi + A_hi*B_lo) => ~fp32-accurate MFMA GEMM.
// Tile 128x128, 4 waves, mfma_f32_16x16x32_bf16, K-chunk = 4 channels (32 k) x {hi,lo}.

#define B_ 4
#define E_ 16384

typedef short short8 __attribute__((ext_vector_type(8)));
typedef float floatx4 __attribute__((ext_vector_type(4)));

__device__ __forceinline__ float lk(float v) { return v > 0.0f ? v : 0.01f * v; }
__device__ __forceinline__ float b2f(__hip_bfloat16 h) { return __bfloat162float(h); }
__device__ __forceinline__ __hip_bfloat16 f2b(float f) { return __float2bfloat16(f); }

template <typename TS>
struct Cvt;
template <>
struct Cvt<float> {
    static __device__ __forceinline__ float to(float f) { return f; }
    static __device__ __forceinline__ float from(float s) { return s; }
    static __device__ __forceinline__ void ld2(const float* p, float& a, float& b) {
        const float2 v = *reinterpret_cast<const float2*>(p);
        a = v.x;
        b = v.y;
    }
};
template <>
struct Cvt<__hip_bfloat16> {
    static __device__ __forceinline__ __hip_bfloat16 to(float f) { return f2b(f); }
    static __device__ __forceinline__ float from(__hip_bfloat16 s) { return b2f(s); }
    static __device__ __forceinline__ void ld2(const __hip_bfloat16* p, float& a, float& b) {
        union {
            unsigned u;
            __hip_bfloat16 h[2];
        } v;
        v.u = *reinterpret_cast<const unsigned*>(p);
        a = b2f(v.h[0]);
        b = b2f(v.h[1]);
    }
};

// ---------------- x [B][128][E] fp32 -> xT [B*E][128] TS ----------------
template <typename TS>
__global__ void k_transpose_x(const float* __restrict__ x, TS* __restrict__ xT) {
    __shared__ float t[32][33];
    const int b = blockIdx.z, c0 = blockIdx.y * 32, e0 = blockIdx.x * 32;
    const int tx = threadIdx.x & 31, ty = threadIdx.x >> 5;
#pragma unroll
    for (int i = 0; i < 4; ++i) {
        const int c = ty + i * 8;
        t[c][tx] = x[((size_t)b * 128 + c0 + c) * E_ + e0 + tx];
    }
    __syncthreads();
#pragma unroll
    for (int i = 0; i < 4; ++i) {
        const int e = ty + i * 8;
        xT[((size_t)b * E_ + e0 + e) * 128 + c0 + tx] = Cvt<TS>::to(t[tx][e]);
    }
}

// ---- W [256][C][7] fp32 -> hi/lo bf16 [256][C*8] (k=c*8+f, f=7 -> 0) ----
__global__ void k_prep_w(const float* __restrict__ w, __hip_bfloat16* __restrict__ wh,
                         __hip_bfloat16* __restrict__ wl, int C) {
    const int idx = blockIdx.x * blockDim.x + threadIdx.x;  // o*C + c
    if (idx >= 256 * C) return;
    const float* src = w + (size_t)idx * 7;
    __hip_bfloat16* dh = wh + (size_t)idx * 8;
    __hip_bfloat16* dl = wl + (size_t)idx * 8;
#pragma unroll
    for (int f = 0; f < 7; ++f) {
        const float v = src[f];
        const __hip_bfloat16 hi = f2b(v);
        dh[f] = hi;
        dl[f] = f2b(v - b2f(hi));
    }
    dh[7] = f2b(0.0f);
    dl[7] = f2b(0.0f);
}

// ---------------- per-channel sum & sumsq of leaky(h), h [B*E][256] ----------------
template <typename TS>
__global__ void k_bn_stats(const TS* __restrict__ h, float* __restrict__ stats) {
    const int c = threadIdx.x;
    const size_t r0 = (size_t)blockIdx.x * 256;
    float s = 0.0f, q = 0.0f;
    for (int r = 0; r < 256; ++r) {
        const float v = lk(Cvt<TS>::from(h[(r0 + r) * 256 + c]));
        s += v;
        q += v * v;
    }
    atomicAdd(&stats[c], s);
    atomicAdd(&stats[256 + c], q);
}

__global__ void k_bn_finalize(const float* __restrict__ stats, const float* __restrict__ gamma,
                              const float* __restrict__ beta, float* __restrict__ scale,
                              float* __restrict__ bias) {
    const int c = threadIdx.x;
    const float n = 1.0f / 65536.0f;
    const float mean = stats[c] * n;
    const float var = stats[256 + c] * n - mean * mean;
    const float inv = rsqrtf(var + 1e-5f);
    const float s = gamma[c] * inv;
    scale[c] = s;
    bias[c] = beta[c] - mean * s;
}

// ---------------- fused gather + features + split-bf16 MFMA GEMM ----------------
// K-chunk = 4 channels = 32 k-elems; LDS cols [0,32)=hi plane, [32,64)=lo plane, stride 72.
template <int C, bool BN, typename TS>
__global__ __launch_bounds__(256, 2) void k_conv(const TS* __restrict__ hin,
                                                 const int* __restrict__ edges,
                                                 const __hip_bfloat16* __restrict__ wh,
                                                 const __hip_bfloat16* __restrict__ wl,
                                                 const float* __restrict__ scale,
                                                 const float* __restrict__ bias,
                                                 TS* __restrict__ hout) {
    constexpr int K = C * 8;
    constexpr int NCH = C / 4;
    constexpr int AS = 72;  // 64 + 8 pad -> 144 B row stride (16B aligned; reads 2-way = free)
    __shared__ __align__(16) __hip_bfloat16 Asm[128 * AS];
    __shared__ __align__(16) __hip_bfloat16 Bsm[128 * AS];
    __shared__ float ssc[C];
    __shared__ float ssb[C];

    const int tid = threadIdx.x;
    const int tm = blockIdx.x;        // 512 m-tiles (128 per batch)
    const int n0 = blockIdx.y * 128;  // 0 or 128
    const int b = tm >> 7;
    const int e0 = (tm & 127) * 128;

    if constexpr (BN) {
        for (int c = tid; c < C; c += 256) {
            ssc[c] = scale[c];
            ssb[c] = bias[c];
        }
    }

    const int e_loc = tid & 127;
    const int c_sub = (tid >> 7) * 2;  // this thread's 2 channels within the 4-chunk
    const int4 nb = *reinterpret_cast<const int4*>(edges + (((size_t)b * E_) + e0 + e_loc) * 4);
    const size_t rb = (size_t)b * E_;
    const TS* rp0 = hin + (rb + e0 + e_loc) * C;
    const TS* rp1 = hin + (rb + nb.x) * C;
    const TS* rp2 = hin + (rb + nb.y) * C;
    const TS* rp3 = hin + (rb + nb.z) * C;
    const TS* rp4 = hin + (rb + nb.w) * C;

    floatx4 acc[4][4];
#pragma unroll
    for (int i = 0; i < 4; ++i)
#pragma unroll
        for (int j = 0; j < 4; ++j) {
            floatx4 z = {0.0f, 0.0f, 0.0f, 0.0f};
            acc[i][j] = z;
        }

    const int wave = tid >> 6, lane = tid & 63;
    const int wm = (wave & 1) * 64, wn = (wave >> 1) * 64;
    const int qd = lane >> 4, l15 = lane & 15;

    if constexpr (BN) __syncthreads();

    for (int ci = 0; ci < NCH; ++ci) {
        const int cg = ci * 4 + c_sub;  // first of my 2 channels
        float g0[2], g1[2], g2[2], g3[2], g4[2];
        Cvt<TS>::ld2(rp0 + cg, g0[0], g0[1]);
        Cvt<TS>::ld2(rp1 + cg, g1[0], g1[1]);
        Cvt<TS>::ld2(rp2 + cg, g2[0], g2[1]);
        Cvt<TS>::ld2(rp3 + cg, g3[0], g3[1]);
        Cvt<TS>::ld2(rp4 + cg, g4[0], g4[1]);
#pragma unroll
        for (int cc = 0; cc < 2; ++cc) {
            float f0 = g0[cc], f1 = g1[cc], f2 = g2[cc], f3 = g3[cc], f4 = g4[cc];
            if constexpr (BN) {
                const float sA = ssc[cg + cc];
                const float bA = ssb[cg + cc];
                f0 = lk(f0) * sA + bA;
                f1 = lk(f1) * sA + bA;
                f2 = lk(f2) * sA + bA;
                f3 = lk(f3) * sA + bA;
                f4 = lk(f4) * sA + bA;
            }
            float gf[8];
            gf[0] = f0;
            gf[1] = f1 + f3;
            gf[2] = f2 + f4;
            gf[3] = fabsf(f1 - f3);
            gf[4] = fabsf(f2 - f4);
            gf[5] = gf[1] + gf[2];
            const float avg = 0.25f * gf[5];
            const float d1 = f1 - avg, d2 = f2 - avg, d3 = f3 - avg, d4 = f4 - avg;
            gf[6] = d1 * d1 + d2 * d2 + d3 * d3 + d4 * d4;
            gf[7] = 0.0f;
            union U {
                short8 v;
                __hip_bfloat16 h[8];
            } uh, ul;
#pragma unroll
            for (int f = 0; f < 8; ++f) {
                const __hip_bfloat16 hi = f2b(gf[f]);
                uh.h[f] = hi;
                ul.h[f] = f2b(gf[f] - b2f(hi));
            }
            const int col = (c_sub + cc) * 8;
            *reinterpret_cast<short8*>(&Asm[e_loc * AS + col]) = uh.v;
            *reinterpret_cast<short8*>(&Asm[e_loc * AS + 32 + col]) = ul.v;
        }
        // ---- stage B: rows n0..n0+127, 32 k-elems per plane
        const int k0 = ci * 32;
#pragma unroll
        for (int i = 0; i < 2; ++i) {
            const int j = tid + i * 256;
            const int row = j >> 2, part = j & 3;
            const size_t gofs = (size_t)(n0 + row) * K + k0 + part * 8;
            *reinterpret_cast<uint4*>(&Bsm[row * AS + part * 8]) =
                *reinterpret_cast<const uint4*>(wh + gofs);
            *reinterpret_cast<uint4*>(&Bsm[row * AS + 32 + part * 8]) =
                *reinterpret_cast<const uint4*>(wl + gofs);
        }
        __syncthreads();
        // ---- MFMA: 3-product split
        const int colh = qd * 8, coll = 32 + qd * 8;
        short8 ah[4], al[4], bh[4], bl[4];
#pragma unroll
        for (int mt = 0; mt < 4; ++mt) {
            const int r = (wm + mt * 16 + l15) * AS;
            ah[mt] = *reinterpret_cast<const short8*>(&Asm[r + colh]);
            al[mt] = *reinterpret_cast<const short8*>(&Asm[r + coll]);
        }
#pragma unroll
        for (int nt = 0; nt < 4; ++nt) {
            const int r = (wn + nt * 16 + l15) * AS;
            bh[nt] = *reinterpret_cast<const short8*>(&Bsm[r + colh]);
            bl[nt] = *reinterpret_cast<const short8*>(&Bsm[r + coll]);
        }
#pragma unroll
        for (int mt = 0; mt < 4; ++mt)
#pragma unroll
            for (int nt = 0; nt < 4; ++nt) {
                acc[mt][nt] =
                    __builtin_amdgcn_mfma_f32_16x16x32_bf16(ah[mt], bh[nt], acc[mt][nt], 0, 0, 0);
                acc[mt][nt] =
                    __builtin_amdgcn_mfma_f32_16x16x32_bf16(al[mt], bh[nt], acc[mt][nt], 0, 0, 0);
                acc[mt][nt] =
                    __builtin_amdgcn_mfma_f32_16x16x32_bf16(ah[mt], bl[nt], acc[mt][nt], 0, 0, 0);
            }
        __syncthreads();
    }

    // ---- epilogue: C/D layout col = lane&15, row = (lane>>4)*4 + reg
    const size_t orow0 = (size_t)b * E_ + e0;
#pragma unroll
    for (int mt = 0; mt < 4; ++mt) {
#pragma unroll
        for (int nt = 0; nt < 4; ++nt) {
            const int col = n0 + wn + nt * 16 + l15;
            const size_t r0 = orow0 + wm + mt * 16 + qd * 4;
#pragma unroll
            for (int r = 0; r < 4; ++r) hout[(r0 + r) * 256 + col] = Cvt<TS>::to(acc[mt][nt][r]);
        }
    }
}

// ---------------- out[b][o][e] = leaky(h + h1), fp32, transposed write ----------------
template <typename TS>
__global__ void k_final(const TS* __restrict__ h, const TS* __restrict__ h1,
                        float* __restrict__ out) {
    __shared__ float t[32][33];
    const int b = blockIdx.z, o0 = blockIdx.y * 32, e0 = blockIdx.x * 32;
    const int tx = threadIdx.x & 31, ty = threadIdx.x >> 5;
#pragma unroll
    for (int i = 0; i < 4; ++i) {
        const int e = ty + i * 8;
        const size_t idx = ((size_t)b * E_ + e0 + e) * 256 + o0 + tx;
        t[e][tx] = lk(Cvt<TS>::from(h[idx]) + Cvt<TS>::from(h1[idx]));
    }
    __syncthreads();
#pragma unroll
    for (int i = 0; i < 4; ++i) {
        const int o = ty + i * 8;
        out[((size_t)b * 256 + o0 + o) * E_ + e0 + tx] = t[tx][o];
    }
}

template <typename TS>
static void run_all(const float* x, const int* edges, const float* W0, const float* Ws,
                    const float* gammas, const float* betas, float* out, char* ws,
                    hipStream_t stream) {
    const size_t hbytes = (size_t)B_ * E_ * 256 * sizeof(TS);
    TS* h1 = (TS*)(ws);
    TS* hA = (TS*)(ws + hbytes);
    TS* hB = (TS*)(ws + 2 * hbytes);
    TS* xT = (TS*)(ws + 2 * hbytes);  // alias hB: dead before conv3 writes hB
    char* wp = ws + 3 * hbytes;
    __hip_bfloat16* w0h = (__hip_bfloat16*)(wp);
    __hip_bfloat16* w0l = (__hip_bfloat16*)(wp + 524288);
    __hip_bfloat16* wsh[3], *wsl[3];
    for (int i = 0; i < 3; ++i) {
        wsh[i] = (__hip_bfloat16*)(wp + 1048576 + (size_t)i * 2097152);
        wsl[i] = (__hip_bfloat16*)(wp + 1048576 + (size_t)i * 2097152 + 1048576);
    }
    float* stats = (float*)(wp + 7340032);
    float* scale = (float*)(wp + 7342080);
    float* bias = (float*)(wp + 7343104);

    k_transpose_x<TS><<<dim3(E_ / 32, 4, B_), 256, 0, stream>>>(x, xT);
    k_prep_w<<<128, 256, 0, stream>>>(W0, w0h, w0l, 128);
    for (int i = 0; i < 3; ++i)
        k_prep_w<<<256, 256, 0, stream>>>(Ws + (size_t)i * 458752, wsh[i], wsl[i], 256);

    const dim3 gconv(512, 2);
    k_conv<128, false, TS><<<gconv, 256, 0, stream>>>(xT, edges, w0h, w0l, nullptr, nullptr, h1);

    TS* bin[3] = {h1, hA, hB};
    TS* bout[3] = {hA, hB, hA};
    for (int i = 0; i < 3; ++i) {
        hipMemsetAsync(stats, 0, 512 * sizeof(float), stream);
        k_bn_stats<TS><<<256, 256, 0, stream>>>(bin[i], stats);
        k_bn_finalize<<<1, 256, 0, stream>>>(stats, gammas + 256 * i, betas + 256 * i, scale, bias);
        k_conv<256, true, TS><<<gconv, 256, 0, stream>>>(bin[i], edges, wsh[i], wsl[i], scale, bias,
                                                         bout[i]);
    }
    k_final<TS><<<dim3(E_ / 32, 256 / 32, B_), 256, 0, stream>>>(hA, h1, out);
}

extern "C" void kernel_launch(void* const* d_in, const int* in_sizes, int n_in, void* d_out,
                              int out_size, void* d_ws, size_t ws_size, hipStream_t stream) {
    const float* x = (const float*)d_in[0];
    const int* edges = (const int*)d_in[1];
    const float* W0 = (const float*)d_in[2];
    const float* Ws = (const float*)d_in[3];
    const float* gammas = (const float*)d_in[4];
    const float* betas = (const float*)d_in[5];
    float* out = (float*)d_out;
    char* ws = (char*)d_ws;

    // fp32-h path needs 3*64MB + ~7.1MB of weights/stats = 208,670,720 B.
    if (ws_size >= 208670720ULL + 4096ULL)
        run_all<float>(x, edges, W0, Ws, gammas, betas, out, ws, stream);
    else
        run_all<__hip_bfloat16>(x, edges, W0, Ws, gammas, betas, out, ws, stream);
}

// Round 3
// 1767.948 us; speedup vs baseline: 1.1293x; 1.1293x over previous
//
#include <hip/hip_runtime.h>
#include <hip/hip_bf16.h>

// MeshConvNet on MI355X (gfx950) — round 3: latency-hiding round.
// Changes vs r2: (1) n-halves merged (one 512-thr block does 128 edges x 256 outs:
// gather+feature work halves), (2) software-pipelined gather+B staging (next chunk's
// loads issued before the barrier, consumed next iter -> latency overlapped with MFMA),
// (3) per-barrier MFMA doubles. Numerics unchanged (3-product split-bf16, fp32 h).

#define B_ 4
#define E_ 16384

typedef short short8 __attribute__((ext_vector_type(8)));
typedef float floatx4 __attribute__((ext_vector_type(4)));

__device__ __forceinline__ float lk(float v) { return v > 0.0f ? v : 0.01f * v; }
__device__ __forceinline__ float b2f(__hip_bfloat16 h) { return __bfloat162float(h); }
__device__ __forceinline__ __hip_bfloat16 f2b(float f) { return __float2bfloat16(f); }

template <typename TS>
struct Cvt;
template <>
struct Cvt<float> {
    static __device__ __forceinline__ float to(float f) { return f; }
    static __device__ __forceinline__ float from(float s) { return s; }
};
template <>
struct Cvt<__hip_bfloat16> {
    static __device__ __forceinline__ __hip_bfloat16 to(float f) { return f2b(f); }
    static __device__ __forceinline__ float from(__hip_bfloat16 s) { return b2f(s); }
};

// ---------------- x [B][128][E] fp32 -> xT [B*E][128] TS ----------------
template <typename TS>
__global__ void k_transpose_x(const float* __restrict__ x, TS* __restrict__ xT) {
    __shared__ float t[32][33];
    const int b = blockIdx.z, c0 = blockIdx.y * 32, e0 = blockIdx.x * 32;
    const int tx = threadIdx.x & 31, ty = threadIdx.x >> 5;
#pragma unroll
    for (int i = 0; i < 4; ++i) {
        const int c = ty + i * 8;
        t[c][tx] = x[((size_t)b * 128 + c0 + c) * E_ + e0 + tx];
    }
    __syncthreads();
#pragma unroll
    for (int i = 0; i < 4; ++i) {
        const int e = ty + i * 8;
        xT[((size_t)b * E_ + e0 + e) * 128 + c0 + tx] = Cvt<TS>::to(t[tx][e]);
    }
}

// ---- W [256][C][7] fp32 -> hi/lo bf16 [256][C*8] (k=c*8+f, f=7 -> 0) ----
__global__ void k_prep_w(const float* __restrict__ w, __hip_bfloat16* __restrict__ wh,
                         __hip_bfloat16* __restrict__ wl, int C) {
    const int idx = blockIdx.x * blockDim.x + threadIdx.x;  // o*C + c
    if (idx >= 256 * C) return;
    const float* src = w + (size_t)idx * 7;
    __hip_bfloat16* dh = wh + (size_t)idx * 8;
    __hip_bfloat16* dl = wl + (size_t)idx * 8;
#pragma unroll
    for (int f = 0; f < 7; ++f) {
        const float v = src[f];
        const __hip_bfloat16 hi = f2b(v);
        dh[f] = hi;
        dl[f] = f2b(v - b2f(hi));
    }
    dh[7] = f2b(0.0f);
    dl[7] = f2b(0.0f);
}

// ---------------- per-channel sum & sumsq of leaky(h), h [B*E][256] ----------------
template <typename TS>
__global__ void k_bn_stats(const TS* __restrict__ h, float* __restrict__ stats) {
    const int c = threadIdx.x;
    const size_t r0 = (size_t)blockIdx.x * 256;
    float s = 0.0f, q = 0.0f;
    for (int r = 0; r < 256; ++r) {
        const float v = lk(Cvt<TS>::from(h[(r0 + r) * 256 + c]));
        s += v;
        q += v * v;
    }
    atomicAdd(&stats[c], s);
    atomicAdd(&stats[256 + c], q);
}

__global__ void k_bn_finalize(const float* __restrict__ stats, const float* __restrict__ gamma,
                              const float* __restrict__ beta, float* __restrict__ scale,
                              float* __restrict__ bias) {
    const int c = threadIdx.x;
    const float n = 1.0f / 65536.0f;
    const float mean = stats[c] * n;
    const float var = stats[256 + c] * n - mean * mean;
    const float inv = rsqrtf(var + 1e-5f);
    const float s = gamma[c] * inv;
    scale[c] = s;
    bias[c] = beta[c] - mean * s;
}

// ---------------- fused gather + features + split-bf16 MFMA GEMM ----------------
// 512 thr = 8 waves; tile 128 edges x 256 outs; K-chunk = 4 channels (32 k) x {hi,lo}.
// Pipelined: chunk ci+1's gather + B loads are in flight during chunk ci's MFMA.
template <int C, bool BN, typename TS>
__global__ __launch_bounds__(512, 2) void k_conv(const TS* __restrict__ hin,
                                                 const int* __restrict__ edges,
                                                 const __hip_bfloat16* __restrict__ wh,
                                                 const __hip_bfloat16* __restrict__ wl,
                                                 const float* __restrict__ scale,
                                                 const float* __restrict__ bias,
                                                 TS* __restrict__ hout) {
    constexpr int K = C * 8;
    constexpr int NCH = C / 4;
    constexpr int AS = 72;  // 64 + 8 pad shorts -> 144 B row stride
    __shared__ __align__(16) __hip_bfloat16 Asm[128 * AS];
    __shared__ __align__(16) __hip_bfloat16 Bsm[256 * AS];
    __shared__ float ssc[C];
    __shared__ float ssb[C];

    const int tid = threadIdx.x;
    const int tm = blockIdx.x;  // 512 m-tiles (128 per batch)
    const int b = tm >> 7;
    const int e0 = (tm & 127) * 128;

    if constexpr (BN) {
        if (tid < C) {
            ssc[tid] = scale[tid];
            ssb[tid] = bias[tid];
        }
    }

    // ---- A-gather assignment: 128 edges x 4 channel-threads
    const int e_loc = tid & 127;
    const int c_sub = tid >> 7;  // my channel within the 4-chunk (0..3)
    const int4 nb = *reinterpret_cast<const int4*>(edges + (((size_t)b * E_) + e0 + e_loc) * 4);
    const size_t rb = (size_t)b * E_;
    const TS* rp0 = hin + (rb + e0 + e_loc) * C + c_sub;
    const TS* rp1 = hin + (rb + nb.x) * C + c_sub;
    const TS* rp2 = hin + (rb + nb.y) * C + c_sub;
    const TS* rp3 = hin + (rb + nb.z) * C + c_sub;
    const TS* rp4 = hin + (rb + nb.w) * C + c_sub;

    // ---- B-staging assignment: 256 rows x 2 threads (2 x uint4 per plane each)
    const int brow = tid >> 1;
    const int bq = tid & 1;
    const __hip_bfloat16* whp = wh + (size_t)brow * K + bq * 16;
    const __hip_bfloat16* wlp = wl + (size_t)brow * K + bq * 16;

    floatx4 acc[4][4];
#pragma unroll
    for (int i = 0; i < 4; ++i)
#pragma unroll
        for (int j = 0; j < 4; ++j) {
            floatx4 z = {0.0f, 0.0f, 0.0f, 0.0f};
            acc[i][j] = z;
        }

    const int wave = tid >> 6, lane = tid & 63;
    const int wm = (wave & 1) * 64;         // 0 / 64
    const int wn = (wave >> 1) * 64;        // 0 / 64 / 128 / 192
    const int qd = lane >> 4, l15 = lane & 15;

    // ---- pipeline preload: chunk 0
    float pA0 = Cvt<TS>::from(rp0[0]);
    float pA1 = Cvt<TS>::from(rp1[0]);
    float pA2 = Cvt<TS>::from(rp2[0]);
    float pA3 = Cvt<TS>::from(rp3[0]);
    float pA4 = Cvt<TS>::from(rp4[0]);
    uint4 wBh0 = *reinterpret_cast<const uint4*>(whp);
    uint4 wBh1 = *reinterpret_cast<const uint4*>(whp + 8);
    uint4 wBl0 = *reinterpret_cast<const uint4*>(wlp);
    uint4 wBl1 = *reinterpret_cast<const uint4*>(wlp + 8);

    if constexpr (BN) __syncthreads();  // ssc/ssb visible before first feature compute

    for (int ci = 0; ci < NCH; ++ci) {
        // ---- stage A: features for my (edge, channel) from prefetched regs
        {
            float f0 = pA0, f1 = pA1, f2 = pA2, f3 = pA3, f4 = pA4;
            if constexpr (BN) {
                const float sA = ssc[ci * 4 + c_sub];
                const float bA = ssb[ci * 4 + c_sub];
                f0 = lk(f0) * sA + bA;
                f1 = lk(f1) * sA + bA;
                f2 = lk(f2) * sA + bA;
                f3 = lk(f3) * sA + bA;
                f4 = lk(f4) * sA + bA;
            }
            float gf[8];
            gf[0] = f0;
            gf[1] = f1 + f3;
            gf[2] = f2 + f4;
            gf[3] = fabsf(f1 - f3);
            gf[4] = fabsf(f2 - f4);
            gf[5] = gf[1] + gf[2];
            const float avg = 0.25f * gf[5];
            const float d1 = f1 - avg, d2 = f2 - avg, d3 = f3 - avg, d4 = f4 - avg;
            gf[6] = d1 * d1 + d2 * d2 + d3 * d3 + d4 * d4;
            gf[7] = 0.0f;
            union U {
                short8 v;
                __hip_bfloat16 h[8];
            } uh, ul;
#pragma unroll
            for (int f = 0; f < 8; ++f) {
                const __hip_bfloat16 hi = f2b(gf[f]);
                uh.h[f] = hi;
                ul.h[f] = f2b(gf[f] - b2f(hi));
            }
            *reinterpret_cast<short8*>(&Asm[e_loc * AS + c_sub * 8]) = uh.v;
            *reinterpret_cast<short8*>(&Asm[e_loc * AS + 32 + c_sub * 8]) = ul.v;
        }
        // ---- stage B from prefetched regs
        *reinterpret_cast<uint4*>(&Bsm[brow * AS + bq * 16]) = wBh0;
        *reinterpret_cast<uint4*>(&Bsm[brow * AS + bq * 16 + 8]) = wBh1;
        *reinterpret_cast<uint4*>(&Bsm[brow * AS + 32 + bq * 16]) = wBl0;
        *reinterpret_cast<uint4*>(&Bsm[brow * AS + 32 + bq * 16 + 8]) = wBl1;

        // ---- issue next chunk's loads (in flight across barrier + MFMA)
        float nA0, nA1, nA2, nA3, nA4;
        uint4 nBh0, nBh1, nBl0, nBl1;
        if (ci + 1 < NCH) {
            const int co = (ci + 1) * 4;
            nA0 = Cvt<TS>::from(rp0[co]);
            nA1 = Cvt<TS>::from(rp1[co]);
            nA2 = Cvt<TS>::from(rp2[co]);
            nA3 = Cvt<TS>::from(rp3[co]);
            nA4 = Cvt<TS>::from(rp4[co]);
            const int ko = (ci + 1) * 32;
            nBh0 = *reinterpret_cast<const uint4*>(whp + ko);
            nBh1 = *reinterpret_cast<const uint4*>(whp + ko + 8);
            nBl0 = *reinterpret_cast<const uint4*>(wlp + ko);
            nBl1 = *reinterpret_cast<const uint4*>(wlp + ko + 8);
        }
        __syncthreads();

        // ---- MFMA: 4x4 tiles x 3-product split
        const int colh = qd * 8, coll = 32 + qd * 8;
        short8 ah[4], al[4], bh[4], bl[4];
#pragma unroll
        for (int mt = 0; mt < 4; ++mt) {
            const int r = (wm + mt * 16 + l15) * AS;
            ah[mt] = *reinterpret_cast<const short8*>(&Asm[r + colh]);
            al[mt] = *reinterpret_cast<const short8*>(&Asm[r + coll]);
        }
#pragma unroll
        for (int nt = 0; nt < 4; ++nt) {
            const int r = (wn + nt * 16 + l15) * AS;
            bh[nt] = *reinterpret_cast<const short8*>(&Bsm[r + colh]);
            bl[nt] = *reinterpret_cast<const short8*>(&Bsm[r + coll]);
        }
#pragma unroll
        for (int mt = 0; mt < 4; ++mt)
#pragma unroll
            for (int nt = 0; nt < 4; ++nt) {
                acc[mt][nt] =
                    __builtin_amdgcn_mfma_f32_16x16x32_bf16(ah[mt], bh[nt], acc[mt][nt], 0, 0, 0);
                acc[mt][nt] =
                    __builtin_amdgcn_mfma_f32_16x16x32_bf16(al[mt], bh[nt], acc[mt][nt], 0, 0, 0);
                acc[mt][nt] =
                    __builtin_amdgcn_mfma_f32_16x16x32_bf16(ah[mt], bl[nt], acc[mt][nt], 0, 0, 0);
            }
        __syncthreads();

        // ---- rotate pipeline regs (vmcnt waits land here, after the MFMA phase)
        if (ci + 1 < NCH) {
            pA0 = nA0; pA1 = nA1; pA2 = nA2; pA3 = nA3; pA4 = nA4;
            wBh0 = nBh0; wBh1 = nBh1; wBl0 = nBl0; wBl1 = nBl1;
        }
    }

    // ---- epilogue: C/D layout col = lane&15, row = (lane>>4)*4 + reg
    const size_t orow0 = (size_t)b * E_ + e0;
#pragma unroll
    for (int mt = 0; mt < 4; ++mt) {
#pragma unroll
        for (int nt = 0; nt < 4; ++nt) {
            const int col = wn + nt * 16 + l15;
            const size_t r0 = orow0 + wm + mt * 16 + qd * 4;
#pragma unroll
            for (int r = 0; r < 4; ++r) hout[(r0 + r) * 256 + col] = Cvt<TS>::to(acc[mt][nt][r]);
        }
    }
}

// ---------------- out[b][o][e] = leaky(h + h1), fp32, transposed write ----------------
template <typename TS>
__global__ void k_final(const TS* __restrict__ h, const TS* __restrict__ h1,
                        float* __restrict__ out) {
    __shared__ float t[32][33];
    const int b = blockIdx.z, o0 = blockIdx.y * 32, e0 = blockIdx.x * 32;
    const int tx = threadIdx.x & 31, ty = threadIdx.x >> 5;
#pragma unroll
    for (int i = 0; i < 4; ++i) {
        const int e = ty + i * 8;
        const size_t idx = ((size_t)b * E_ + e0 + e) * 256 + o0 + tx;
        t[e][tx] = lk(Cvt<TS>::from(h[idx]) + Cvt<TS>::from(h1[idx]));
    }
    __syncthreads();
#pragma unroll
    for (int i = 0; i < 4; ++i) {
        const int o = ty + i * 8;
        out[((size_t)b * 256 + o0 + o) * E_ + e0 + tx] = t[tx][o];
    }
}

template <typename TS>
static void run_all(const float* x, const int* edges, const float* W0, const float* Ws,
                    const float* gammas, const float* betas, float* out, char* ws,
                    hipStream_t stream) {
    const size_t hbytes = (size_t)B_ * E_ * 256 * sizeof(TS);
    TS* h1 = (TS*)(ws);
    TS* hA = (TS*)(ws + hbytes);
    TS* hB = (TS*)(ws + 2 * hbytes);
    TS* xT = (TS*)(ws + 2 * hbytes);  // alias hB: dead before conv3 writes hB
    char* wp = ws + 3 * hbytes;
    __hip_bfloat16* w0h = (__hip_bfloat16*)(wp);
    __hip_bfloat16* w0l = (__hip_bfloat16*)(wp + 524288);
    __hip_bfloat16* wsh[3], *wsl[3];
    for (int i = 0; i < 3; ++i) {
        wsh[i] = (__hip_bfloat16*)(wp + 1048576 + (size_t)i * 2097152);
        wsl[i] = (__hip_bfloat16*)(wp + 1048576 + (size_t)i * 2097152 + 1048576);
    }
    float* stats = (float*)(wp + 7340032);
    float* scale = (float*)(wp + 7342080);
    float* bias = (float*)(wp + 7343104);

    k_transpose_x<TS><<<dim3(E_ / 32, 4, B_), 256, 0, stream>>>(x, xT);
    k_prep_w<<<128, 256, 0, stream>>>(W0, w0h, w0l, 128);
    for (int i = 0; i < 3; ++i)
        k_prep_w<<<256, 256, 0, stream>>>(Ws + (size_t)i * 458752, wsh[i], wsl[i], 256);

    const dim3 gconv(512);
    k_conv<128, false, TS><<<gconv, 512, 0, stream>>>(xT, edges, w0h, w0l, nullptr, nullptr, h1);

    TS* bin[3] = {h1, hA, hB};
    TS* bout[3] = {hA, hB, hA};
    for (int i = 0; i < 3; ++i) {
        hipMemsetAsync(stats, 0, 512 * sizeof(float), stream);
        k_bn_stats<TS><<<256, 256, 0, stream>>>(bin[i], stats);
        k_bn_finalize<<<1, 256, 0, stream>>>(stats, gammas + 256 * i, betas + 256 * i, scale, bias);
        k_conv<256, true, TS><<<gconv, 512, 0, stream>>>(bin[i], edges, wsh[i], wsl[i], scale, bias,
                                                         bout[i]);
    }
    k_final<TS><<<dim3(E_ / 32, 256 / 32, B_), 256, 0, stream>>>(hA, h1, out);
}

extern "C" void kernel_launch(void* const* d_in, const int* in_sizes, int n_in, void* d_out,
                              int out_size, void* d_ws, size_t ws_size, hipStream_t stream) {
    const float* x = (const float*)d_in[0];
    const int* edges = (const int*)d_in[1];
    const float* W0 = (const float*)d_in[2];
    const float* Ws = (const float*)d_in[3];
    const float* gammas = (const float*)d_in[4];
    const float* betas = (const float*)d_in[5];
    float* out = (float*)d_out;
    char* ws = (char*)d_ws;

    // fp32-h path needs 3*64MB + ~7.1MB of weights/stats = 208,670,720 B.
    if (ws_size >= 208670720ULL + 4096ULL)
        run_all<float>(x, edges, W0, Ws, gammas, betas, out, ws, stream);
    else
        run_all<__hip_bfloat16>(x, edges, W0, Ws, gammas, betas, out, ws, stream);
}